// Round 7
// baseline (230.910 us; speedup 1.0000x reference)
//
#include <hip/hip_runtime.h>
#include <hip/hip_bf16.h>

// Problem: B=4, S=2048, D=1024, H=16, E=64
#define B_ 4
#define S_ 2048
#define D_ 1024
#define H_ 16
#define E_ 64
#define M_ (B_*S_)      // 8192 rows
#define NQKV_ 3072

typedef __attribute__((ext_vector_type(8))) short bf16x8;
typedef __attribute__((ext_vector_type(4))) float f32x4;
typedef __attribute__((ext_vector_type(4))) unsigned short u16x4;
typedef unsigned short u16;

#define QSCALE 0.18033688011f   // log2(e)/8: folded into Q at GEMM epilogue

static __device__ __forceinline__ u16 f2bf(float f) {
  unsigned u = __builtin_bit_cast(unsigned, f);
  unsigned r = (u + 0x7FFFu + ((u >> 16) & 1u)) >> 16;
  return (u16)r;
}

// packed RNE f32x2 -> bf16x2 (low = a, high = b)
static __device__ __forceinline__ unsigned pk2(float a, float b) {
  unsigned r;
  asm("v_cvt_pk_bf16_f32 %0, %1, %2" : "=v"(r) : "v"(a), "v"(b));
  return r;
}

// ---------------- conversion kernels ----------------

__global__ __launch_bounds__(256) void cvt4(const float* __restrict__ in,
                                            u16* __restrict__ out, int n4) {
  int i = blockIdx.x * 256 + threadIdx.x;
  if (i >= n4) return;
  f32x4 v = ((const f32x4*)in)[i];
  u16x4 o;
  o.x = f2bf(v.x); o.y = f2bf(v.y); o.z = f2bf(v.z); o.w = f2bf(v.w);
  ((u16x4*)out)[i] = o;
}

// Wq/Wk/Wv [H,D,E] -> Wt [3072][1024] (B^T layout: Wt[n][k] = W[k][n])
__global__ __launch_bounds__(256) void cvt_wqkv(const float* __restrict__ Wq,
                                                const float* __restrict__ Wk,
                                                const float* __restrict__ Wv,
                                                u16* __restrict__ Wt) {
  int idx = blockIdx.x * 256 + threadIdx.x;   // over [H][D][E]
  int e = idx & 63, d = (idx >> 6) & 1023, h = idx >> 16;
  int n = h * 64 + e;
  Wt[(size_t)n * 1024 + d]          = f2bf(Wq[idx]);
  Wt[(size_t)(1024 + n) * 1024 + d] = f2bf(Wk[idx]);
  Wt[(size_t)(2048 + n) * 1024 + d] = f2bf(Wv[idx]);
}

// ---------------- GEMM: C[M,N] = A[M,K] * Bt[N,K]^T ----------------
// 128x128 tile, BK=32, 4 waves (2x2 of 64x64), global_load_lds w=16.
// QKV instance (Vt!=null): bn<8 (Q cols) pre-scaled by QSCALE; bn>=16
// (V cols) written TRANSPOSED into Vt[(b*1024 + (c-2048))*2048 + s].

template<bool FP32OUT>
__global__ __launch_bounds__(256) void gemm_bt(const u16* __restrict__ A,
                                               const u16* __restrict__ Bt,
                                               void* __restrict__ Cv, int ldC,
                                               u16* __restrict__ Vt,
                                               const float* __restrict__ bias,
                                               int M, int N, int K) {
  __shared__ u16 As[128 * 32];
  __shared__ u16 Bs[128 * 32];
  const int tid = threadIdx.x;
  const int lane = tid & 63, wid = tid >> 6;
  const int bm = blockIdx.x, bn = blockIdx.y;
  const int wr = wid >> 1, wc = wid & 1;
  const int ll = lane & 15, lg = lane >> 4;

  f32x4 acc[4][4] = {};

  const int srow = lane >> 2;          // row within 16-row chunk
  const int scol = (lane & 3) * 8;     // element col within BK=32

  for (int k0 = 0; k0 < K; k0 += 32) {
#pragma unroll
    for (int p = 0; p < 2; ++p) {
      int row = p * 64 + wid * 16 + srow;
      const u16* ga = A + (size_t)(bm * 128 + row) * K + k0 + scol;
      __builtin_amdgcn_global_load_lds(
          (const __attribute__((address_space(1))) void*)ga,
          (__attribute__((address_space(3))) void*)(As + p * 2048 + wid * 512),
          16, 0, 0);
      const u16* gb = Bt + (size_t)(bn * 128 + row) * K + k0 + scol;
      __builtin_amdgcn_global_load_lds(
          (const __attribute__((address_space(1))) void*)gb,
          (__attribute__((address_space(3))) void*)(Bs + p * 2048 + wid * 512),
          16, 0, 0);
    }
    __syncthreads();
    bf16x8 af[4], bfr[4];
#pragma unroll
    for (int mi = 0; mi < 4; ++mi)
      af[mi] = *(const bf16x8*)&As[(wr * 64 + mi * 16 + ll) * 32 + lg * 8];
#pragma unroll
    for (int ni = 0; ni < 4; ++ni)
      bfr[ni] = *(const bf16x8*)&Bs[(wc * 64 + ni * 16 + ll) * 32 + lg * 8];
#pragma unroll
    for (int mi = 0; mi < 4; ++mi)
#pragma unroll
      for (int ni = 0; ni < 4; ++ni)
        acc[mi][ni] = __builtin_amdgcn_mfma_f32_16x16x32_bf16(af[mi], bfr[ni],
                                                              acc[mi][ni], 0, 0, 0);
    __syncthreads();
  }

  // epilogue: C/D layout col = lane&15, row = (lane>>4)*4 + reg
  const int crow0 = bm * 128 + wr * 64;
  const int ccol0 = bn * 128 + wc * 64 + ll;
  const bool vblk = (Vt != nullptr) && (bn >= 16);   // uniform per block
  const float qs = (Vt != nullptr && bn < 8) ? QSCALE : 1.0f;
#pragma unroll
  for (int mi = 0; mi < 4; ++mi) {
#pragma unroll
    for (int ni = 0; ni < 4; ++ni) {
      int c = ccol0 + ni * 16;
      if (vblk) {
        int r0 = crow0 + mi * 16 + lg * 4;       // token of j=0 (mult of 4)
        int bb = r0 >> 11, s0 = r0 & 2047;
        u16x4 pkv;
        pkv.x = f2bf(acc[mi][ni][0]); pkv.y = f2bf(acc[mi][ni][1]);
        pkv.z = f2bf(acc[mi][ni][2]); pkv.w = f2bf(acc[mi][ni][3]);
        *(u16x4*)&Vt[((size_t)(bb * 1024 + (c - 2048))) * 2048 + s0] = pkv;
      } else {
#pragma unroll
        for (int j = 0; j < 4; ++j) {
          int r = crow0 + mi * 16 + lg * 4 + j;
          if (FP32OUT) {
            ((float*)Cv)[(size_t)r * ldC + c] = acc[mi][ni][j] + bias[c];
          } else {
            ((u16*)Cv)[(size_t)r * ldC + c] = f2bf(acc[mi][ni][j] * qs);
          }
        }
      }
    }
  }
}

// ---------------- flash attention (causal), swapped-QK^T, T13 defer-max ----
// Grid: 1024 flat blocks, 256 thr = 4 waves x 16 q-rows, QBLK=64, KVBLK=64.
// Block pr handles q-tiles {pr, 31-pr}: 33 k-tiles each -> perfect balance.
// Q PRE-SCALED by log2(e)/8 -> S from MFMA is already in exp2 domain.
// Defer-max (T13): track m_run; only rescale when __any(pm - m_run > 8).
// Between rescales p = exp2(s - m_run) <= 2^8 -> l,o unconditionally finite
// for ANY finite s (robust, unlike R6's no-max which NaN'd).
// kappa(nt, r) = 32*(nt>>1) + 8*(r>>2) + 4*(nt&1) + (r&3); key of s[nt][j]
// at lane lg = kb + 32*(nt>>1) + lg*8 + 4*(nt&1) + j.  (verified R5)

#define SWZ(r) (((((r) & 7) ^ ((((r) >> 3) & 3) << 1))) << 4)

__global__ __launch_bounds__(256) void attn(const u16* __restrict__ QK,
                                            const u16* __restrict__ Vt,
                                            u16* __restrict__ AO) {
  __shared__ u16 Klds[2][4096];      // [key][e] swizzled, 8KB per buffer
  __shared__ u16 Vlds[2][4096];      // V^T [e][key] swizzled

  // XCD-chunked remap: XCD x hosts bh in [x*8, x*8+8) -> K/V fits 4MB L2
  const int wg = blockIdx.x;                 // 0..1023
  const int lin = (wg & 7) * 128 + (wg >> 3);
  const int bh = lin >> 4, pr = lin & 15;
  const int b = bh >> 4, h = bh & 15;
  const int tid = threadIdx.x, lane = tid & 63, wid = tid >> 6;
  const int ll = lane & 15, lg = lane >> 4;

  // ---- hoisted per-lane invariant LDS read offsets (bytes, buffer 0) ----
  int koff[2][4], voff[2][4];
#pragma unroll
  for (int ks = 0; ks < 2; ++ks) {
#pragma unroll
    for (int nt = 0; nt < 4; ++nt) {
      int krow = 32 * (nt >> 1) + ((ll >> 2) << 3) + ((nt & 1) << 2) + (ll & 3);
      koff[ks][nt] = krow * 128 + ((ks * 64 + lg * 16) ^ SWZ(krow));
    }
#pragma unroll
    for (int ent = 0; ent < 4; ++ent) {
      int vrow = ent * 16 + ll;
      voff[ks][ent] = vrow * 128 + ((ks * 64 + lg * 16) ^ SWZ(vrow));
    }
  }

  // ---- hoisted staging source pointers (per-lane), tile-0 based ----
  const int ch0 = wid * 2, ch1 = wid * 2 + 1;            // 1KB LDS chunks
  const int sr0 = ch0 * 8 + (lane >> 3), sr1 = ch1 * 8 + (lane >> 3);
  const int cl0 = ((lane & 7) * 16) ^ SWZ(sr0);
  const int cl1 = ((lane & 7) * 16) ^ SWZ(sr1);
  const char* ksrc0 = (const char*)(QK + (size_t)(b * S_ + sr0) * 2048 + 1024 + h * E_) + cl0;
  const char* ksrc1 = (const char*)(QK + (size_t)(b * S_ + sr1) * 2048 + 1024 + h * E_) + cl1;
  const char* vsrc0 = (const char*)(Vt + (size_t)(bh * 64 + sr0) * 2048) + cl0;
  const char* vsrc1 = (const char*)(Vt + (size_t)(bh * 64 + sr1) * 2048) + cl1;

  auto stage = [&](int buf, int kt) {
    size_t kadv = (size_t)kt << 18;            // kt * 64 rows * 4096 B
    size_t vadv = (size_t)kt << 7;             // kt * 64 cols * 2 B
    char* kd = (char*)&Klds[buf][0];
    char* vd = (char*)&Vlds[buf][0];
    __builtin_amdgcn_global_load_lds(
        (const __attribute__((address_space(1))) void*)(ksrc0 + kadv),
        (__attribute__((address_space(3))) void*)(kd + ch0 * 1024), 16, 0, 0);
    __builtin_amdgcn_global_load_lds(
        (const __attribute__((address_space(1))) void*)(ksrc1 + kadv),
        (__attribute__((address_space(3))) void*)(kd + ch1 * 1024), 16, 0, 0);
    __builtin_amdgcn_global_load_lds(
        (const __attribute__((address_space(1))) void*)(vsrc0 + vadv),
        (__attribute__((address_space(3))) void*)(vd + ch0 * 1024), 16, 0, 0);
    __builtin_amdgcn_global_load_lds(
        (const __attribute__((address_space(1))) void*)(vsrc1 + vadv),
        (__attribute__((address_space(3))) void*)(vd + ch1 * 1024), 16, 0, 0);
  };

  int cur = 0;
  stage(0, 0);                       // phase 0, kt 0

  for (int ph = 0; ph < 2; ++ph) {
    const int qt = ph ? 31 - pr : pr;
    const int nkt = qt + 1;
    const int qbase = qt * 64;
    const int q = qbase + wid * 16 + ll;

    // Q fragments (B-operand, pre-scaled): col = ll (q-row), k = e chunk lg*8
    const u16* qp = QK + (size_t)(b * S_ + q) * 2048 + h * E_;
    bf16x8 qf0 = *(const bf16x8*)(qp + lg * 8);
    bf16x8 qf1 = *(const bf16x8*)(qp + 32 + lg * 8);

    float m_run = -INFINITY;         // running max (exp2 domain)
    float l_part = 0.f;              // per-lane partial sum (reduced at end)
    f32x4 o_acc[4] = {};

    for (int kt = 0; kt < nkt; ++kt) {
      __syncthreads();               // staged buffer `cur` ready
      const bool havenext = (kt + 1 < nkt) || (ph == 0);
      if (havenext) stage(cur ^ 1, (kt + 1 < nkt) ? (kt + 1) : 0);

      const char* kbuf = (const char*)&Klds[0][0] + (cur << 13);
      const char* vbuf = (const char*)&Vlds[0][0] + (cur << 13);

      // S^T = mfma(K, Q): lane -> q-row ll, 16 keys across (nt, j)
      f32x4 s[4] = {};
      __builtin_amdgcn_s_setprio(1);
#pragma unroll
      for (int ks = 0; ks < 2; ++ks) {
        bf16x8 qf = ks ? qf1 : qf0;
#pragma unroll
        for (int nt = 0; nt < 4; ++nt) {
          bf16x8 kf = *(const bf16x8*)(kbuf + koff[ks][nt]);
          s[nt] = __builtin_amdgcn_mfma_f32_16x16x32_bf16(kf, qf, s[nt], 0, 0, 0);
        }
      }
      __builtin_amdgcn_s_setprio(0);

      // causal mask (diag tile only); S already scaled (Q pre-scaled)
      if (kt == qt) {
        const int kb = kt * 64;
#pragma unroll
        for (int nt = 0; nt < 4; ++nt) {
          int keyb = kb + 32 * (nt >> 1) + 4 * (nt & 1) + lg * 8;
#pragma unroll
          for (int j = 0; j < 4; ++j)
            if (keyb + j > q) s[nt][j] = -1e30f;
        }
      }

      // T13 defer-max: reduce tile max over in-lane 16 + 4-lane group
      float pm = -3.0e38f;
#pragma unroll
      for (int nt = 0; nt < 4; ++nt)
#pragma unroll
        for (int j = 0; j < 4; ++j) pm = fmaxf(pm, s[nt][j]);
      pm = fmaxf(pm, __shfl_xor(pm, 16, 64));
      pm = fmaxf(pm, __shfl_xor(pm, 32, 64));
      if (__any(pm - m_run > 8.0f)) {          // rare after first tile
        float mn = fmaxf(m_run, pm);
        float corr = exp2f(m_run - mn);        // 0 on first tile (m=-inf)
        m_run = mn;
        l_part *= corr;
#pragma unroll
        for (int ent = 0; ent < 4; ++ent)
#pragma unroll
          for (int j = 0; j < 4; ++j) o_acc[ent][j] *= corr;
      }

      // fused exp2 -> pack -> PV  (p <= 2^8 guaranteed)
      __builtin_amdgcn_s_setprio(1);
#pragma unroll
      for (int ks = 0; ks < 2; ++ks) {
        float p0 = exp2f(s[2 * ks][0] - m_run);
        float p1 = exp2f(s[2 * ks][1] - m_run);
        float p2 = exp2f(s[2 * ks][2] - m_run);
        float p3 = exp2f(s[2 * ks][3] - m_run);
        float p4_ = exp2f(s[2 * ks + 1][0] - m_run);
        float p5 = exp2f(s[2 * ks + 1][1] - m_run);
        float p6 = exp2f(s[2 * ks + 1][2] - m_run);
        float p7 = exp2f(s[2 * ks + 1][3] - m_run);
        l_part += ((p0 + p1) + (p2 + p3)) + ((p4_ + p5) + (p6 + p7));
        union { unsigned w[4]; bf16x8 v; } pf;
        pf.w[0] = pk2(p0, p1);
        pf.w[1] = pk2(p2, p3);
        pf.w[2] = pk2(p4_, p5);
        pf.w[3] = pk2(p6, p7);
#pragma unroll
        for (int ent = 0; ent < 4; ++ent) {
          bf16x8 vf = *(const bf16x8*)(vbuf + voff[ks][ent]);
          o_acc[ent] = __builtin_amdgcn_mfma_f32_16x16x32_bf16(
              vf, pf.v, o_acc[ent], 0, 0, 0);
        }
      }
      __builtin_amdgcn_s_setprio(0);

      cur ^= 1;
    }

    // single cross-lane l reduce (lanes sharing ll hold same q-row)
    float l_run = l_part;
    l_run += __shfl_xor(l_run, 16, 64);
    l_run += __shfl_xor(l_run, 32, 64);
    float rl = 1.0f / l_run;

    // epilogue: O^T[e = ent*16+lg*4+j][q = ll]; AO write u16x4 along j
#pragma unroll
    for (int ent = 0; ent < 4; ++ent) {
      u16x4 o;
#pragma unroll
      for (int j = 0; j < 4; ++j) o[j] = f2bf(o_acc[ent][j] * rl);
      *(u16x4*)&AO[(size_t)(b * S_ + q) * D_ + h * E_ + ent * 16 + lg * 4] = o;
    }
  }
}

// ---------------- launcher ----------------

extern "C" void kernel_launch(void* const* d_in, const int* in_sizes, int n_in,
                              void* d_out, int out_size, void* d_ws, size_t ws_size,
                              hipStream_t stream) {
  const float* embedded = (const float*)d_in[0];
  const float* Wq = (const float*)d_in[1];
  const float* Wk = (const float*)d_in[2];
  const float* Wv = (const float*)d_in[3];
  const float* Wo = (const float*)d_in[4];
  const float* bo = (const float*)d_in[5];
  float* out = (float*)d_out;

  char* ws = (char*)d_ws;
  u16* X    = (u16*)(ws);                     // [8192][1024]  16 MiB @ 0
  u16* Wqkv = (u16*)(ws + (16u << 20));       // [3072][1024]   6 MiB @ 16M
  u16* WoT  = (u16*)(ws + (22u << 20));       // [1024][1024]   2 MiB @ 22M
  u16* QK   = (u16*)(ws + (24u << 20));       // [8192][2048]  32 MiB @ 24M
  u16* Vt   = (u16*)(ws + (56u << 20));       // [64][64][2048] 16 MiB @ 56M
  u16* AO   = (u16*)(ws + (72u << 20));       // [8192][1024]  16 MiB @ 72M

  // 1) embedded fp32 -> bf16
  cvt4<<<8192, 256, 0, stream>>>(embedded, X, 2097152);
  // 2) W_qkv repack+cast
  cvt_wqkv<<<4096, 256, 0, stream>>>(Wq, Wk, Wv, Wqkv);
  // 3) Wo cast
  cvt4<<<1024, 256, 0, stream>>>(Wo, WoT, 262144);
  // 4) QKV projection: QK normal (stride 2048, Q pre-scaled), V -> Vt
  gemm_bt<false><<<dim3(64, 24), 256, 0, stream>>>(X, Wqkv, QK, 2048, Vt,
                                                   nullptr, M_, NQKV_, 1024);
  // 5) causal flash attention (folded-pair balanced grid)
  attn<<<1024, 256, 0, stream>>>(QK, Vt, AO);
  // 6) output projection + bias -> fp32 d_out
  gemm_bt<true><<<dim3(64, 8), 256, 0, stream>>>(AO, WoT, out, 1024, nullptr,
                                                 bo, M_, 1024, 1024);
}